// Round 6
// baseline (396.762 us; speedup 1.0000x reference)
//
#include <hip/hip_runtime.h>

#define KNN 3
#define EPS 1e-8f
#define B_BATCH 4
#define QPB 16   // queries per block = 4 waves x 4 queries/wave

// ---------------------------------------------------------------------------
// Fused kNN over all 4 stages + the (independent) stage-D skip-copy riding
// along: knn is VALU-bound with an idle HBM pipe, the copy is pure HBM, so
// the 32 MB xf0 -> out[0,64) copy overlaps the knn scan for ~free and is
// removed from the serial mega-kernel below. 16 copy blocks x 4 channels
// (xf0 has 64 channels; round-5 bug was launching 64 blocks -> OOB reads).
//
// kNN: wave-per-4-queries; whole xyz2[b] staged in LDS SoA (lane-consecutive
// reads -> 2-way bank aliasing = free). Each lane scans n2/64 candidates for
// 4 queries simultaneously (shared LDS reads, 4 independent branchless top-3
// insert chains on packed u64 keys dist_bits<<32|idx; dist>=0 so float bit
// order == value order; low-word idx tie-breaks to smaller j like jax
// top_k). 6-step __shfl_xor butterfly with a 6-op merge network (lowest-3 of
// two sorted-3 lists). Lane 0 writes a packed record int4{j0,j1,j2,bits(w0n)}
// + w1n; consumer reconstructs w2n = 1 - w0n - w1n.
// ---------------------------------------------------------------------------
__device__ __forceinline__ unsigned long long u64min(unsigned long long a,
                                                     unsigned long long b) {
    return a < b ? a : b;
}
__device__ __forceinline__ unsigned long long u64max(unsigned long long a,
                                                     unsigned long long b) {
    return a > b ? a : b;
}

struct KnnAll {
    const float* xq[4];
    const float* xs[4];
    int4*  rec[4];    // (B, n1): {j0, j1, j2, float_bits(w0n)}
    float* w1[4];     // (B, n1): w1n
    int n1[4], n2[4], blk0[4];
};

__global__ __launch_bounds__(256) void knn_all_kernel(
    KnnAll P,
    const float* __restrict__ xf0,   // (B, 64, 8192) stage-D skip
    float* __restrict__ out)         // (B, 1984, 8192)
{
    __shared__ float s_x[2048], s_y[2048], s_z[2048];
    const int b  = blockIdx.y;
    const int bx = blockIdx.x;

    if (bx >= 680) {   // 16 skip-copy blocks: xf0 -> out[0,64), no knn deps
        const int t = bx - 680;     // t in [0,16), 4 channels each
        const float4* src = (const float4*)(xf0 + ((size_t)b * 64 + t * 4) * 8192);
        float4*       dst = (float4*)(out + ((size_t)b * 1984 + t * 4) * 8192);
        for (int i = threadIdx.x; i < 4 * 8192 / 4; i += 256)
            dst[i] = src[i];
        return;
    }

    // slot selection with CONSTANT struct indices only (runtime-indexed
    // kernarg arrays can spill to scratch -- rule #20)
    const float* xq; const float* xs; int4* orec; float* ow1;
    int n1, n2, bs;
    if (bx >= P.blk0[3]) {
        xq=P.xq[3]; xs=P.xs[3]; orec=P.rec[3]; ow1=P.w1[3];
        n1=P.n1[3]; n2=P.n2[3]; bs=bx-P.blk0[3];
    } else if (bx >= P.blk0[2]) {
        xq=P.xq[2]; xs=P.xs[2]; orec=P.rec[2]; ow1=P.w1[2];
        n1=P.n1[2]; n2=P.n2[2]; bs=bx-P.blk0[2];
    } else if (bx >= P.blk0[1]) {
        xq=P.xq[1]; xs=P.xs[1]; orec=P.rec[1]; ow1=P.w1[1];
        n1=P.n1[1]; n2=P.n2[1]; bs=bx-P.blk0[1];
    } else {
        xq=P.xq[0]; xs=P.xs[0]; orec=P.rec[0]; ow1=P.w1[0];
        n1=P.n1[0]; n2=P.n2[0]; bs=bx;
    }

    const float* src2 = xs + (size_t)b * n2 * 3;
    for (int i = threadIdx.x; i < n2; i += blockDim.x) {
        s_x[i] = src2[i * 3 + 0];
        s_y[i] = src2[i * 3 + 1];
        s_z[i] = src2[i * 3 + 2];
    }
    __syncthreads();

    const int lane = threadIdx.x & 63;
    const int wave = threadIdx.x >> 6;
    const int q0 = bs * QPB + wave * 4;

    float qx[4], qy[4], qz[4];
#pragma unroll
    for (int r = 0; r < 4; ++r) {
        const float* p = xq + ((size_t)b * n1 + q0 + r) * 3;
        qx[r] = p[0]; qy[r] = p[1]; qz[r] = p[2];
    }

    unsigned long long k0[4], k1[4], k2[4];
#pragma unroll
    for (int r = 0; r < 4; ++r) { k0[r] = ~0ull; k1[r] = ~0ull; k2[r] = ~0ull; }

    for (int j = lane; j < n2; j += 64) {
        const float sx = s_x[j], sy = s_y[j], sz = s_z[j];
#pragma unroll
        for (int r = 0; r < 4; ++r) {
            const float dx = qx[r] - sx;
            const float dy = qy[r] - sy;
            const float dz = qz[r] - sz;
            const float d = fmaf(dz, dz, fmaf(dy, dy, dx * dx));
            const unsigned long long key =
                ((unsigned long long)__float_as_uint(d) << 32) | (unsigned)j;
            const unsigned long long u = u64max(key, k0[r]);
            k0[r] = u64min(key, k0[r]);
            const unsigned long long v = u64max(u, k1[r]);
            k1[r] = u64min(u, k1[r]);
            k2[r] = u64min(v, k2[r]);
        }
    }

#pragma unroll
    for (int r = 0; r < 4; ++r) {
        // butterfly merge: both partners compute the same lowest-3 of the
        // two sorted triples (symmetric network), so all lanes converge.
#pragma unroll
        for (int m = 1; m < 64; m <<= 1) {
            const unsigned long long b0 = __shfl_xor(k0[r], m, 64);
            const unsigned long long b1 = __shfl_xor(k1[r], m, 64);
            const unsigned long long b2 = __shfl_xor(k2[r], m, 64);
            const unsigned long long c0 = u64min(k0[r], b0);
            const unsigned long long mm = u64max(k0[r], b0);
            const unsigned long long nn = u64min(k1[r], b1);
            const unsigned long long c1 = u64min(mm, nn);
            const unsigned long long c2 =
                u64min(u64max(mm, nn), u64min(k2[r], b2));
            k0[r] = c0; k1[r] = c1; k2[r] = c2;
        }
        if (lane == 0) {
            const float d0 = __uint_as_float((unsigned)(k0[r] >> 32));
            const float d1 = __uint_as_float((unsigned)(k1[r] >> 32));
            const float d2 = __uint_as_float((unsigned)(k2[r] >> 32));
            float w0 = 1.0f / (d0 + EPS);
            float w1 = 1.0f / (d1 + EPS);
            float w2 = 1.0f / (d2 + EPS);
            const float inv = 1.0f / (w0 + w1 + w2);
            const size_t o = (size_t)b * n1 + q0 + r;
            int4 rec;
            rec.x = (int)(unsigned)(k0[r] & 0xFFFFFFFFu);
            rec.y = (int)(unsigned)(k1[r] & 0xFFFFFFFFu);
            rec.z = (int)(unsigned)(k2[r] & 0xFFFFFFFFu);
            rec.w = __float_as_int(w0 * inv);
            orec[o] = rec;
            ow1[o]  = w1 * inv;
        }
    }
}

// ---------------------------------------------------------------------------
// Mega-kernel: the ENTIRE decoder cascade in one launch. The channel mapping
// is bijective end-to-end: D output tile [64+cD0, 64+cD0+4) consumes exactly
// stage-C channels cD0..cD0+3, which consume B channels cD0-128, which
// consume A channels cD0-384, which consume xf4 channels cD0-896. Each block
// starts at the shallowest level that sources its 4 channels from a real
// input, then gathers up the cascade entirely in LDS:
//   32 pts (s4) --recA--> 128 (s3) --recB--> 512 (s2) --recC--> 2048 (s)
//   --recD--> 8192 output rows.
// s3/s4 are aliased into s (dead by the time s is written) -> 40 KB LDS.
// Phase 2: 4 queries/thread with float4 stores (4x fewer store insts on the
// 260 MB output stream). Deliberately NO launch_bounds min-waves cap and
// #pragma unroll 1 -- round 2 showed that cap+unroll-2 spills to scratch and
// regresses; this is the round-2-proven-correct layout minus those triggers.
// ---------------------------------------------------------------------------
__device__ __forceinline__ float4 gath4(const float* s, const int4 r,
                                        const float w1) {
    const float w0 = __int_as_float(r.w);
    const float w2 = 1.0f - w0 - w1;
    const float4 g0 = *(const float4*)(s + r.x * 4);
    const float4 g1 = *(const float4*)(s + r.y * 4);
    const float4 g2 = *(const float4*)(s + r.z * 4);
    float4 v;
    v.x = w0 * g0.x + w1 * g1.x + w2 * g2.x;
    v.y = w0 * g0.y + w1 * g1.y + w2 * g2.y;
    v.z = w0 * g0.z + w1 * g1.z + w2 * g2.z;
    v.w = w0 * g0.w + w1 * g1.w + w2 * g2.w;
    return v;
}

__global__ __launch_bounds__(256) void mega_kernel(
    const float* __restrict__ xf1,   // (B,  128, 2048)
    const float* __restrict__ xf2,   // (B,  256,  512)
    const float* __restrict__ xf3,   // (B,  512,  128)
    const float* __restrict__ xf4,   // (B, 1024,   32)
    const int4*  __restrict__ recA, const float* __restrict__ w1A,  // (B,128)
    const int4*  __restrict__ recB, const float* __restrict__ w1B,  // (B,512)
    const int4*  __restrict__ recC, const float* __restrict__ w1C,  // (B,2048)
    const int4*  __restrict__ recD, const float* __restrict__ w1D,  // (B,8192)
    float* __restrict__ out)         // (B, 1984, 8192)
{
    const int n1 = 8192, c_out = 1984;
    __shared__ __align__(16) float s [2048 * 4];   // 32 KB, s[j*4+c]
    __shared__ __align__(16) float s2[ 512 * 4];   //  8 KB
    float* s3 = s;         // 128*4 floats, aliased: dead before s is written
    float* s4 = s + 512;   //  32*4 floats, disjoint from s3

    const int b   = blockIdx.y;
    const int bx  = blockIdx.x;
    const int tid = threadIdx.x;

    // longest-cascade-first block ordering (all branches block-uniform)
    int cD0, level;
    if (bx < 256)      { cD0 = 896 + bx * 4;         level = 4; }  // xf4 deep
    else if (bx < 384) { cD0 = 384 + (bx - 256) * 4; level = 3; }  // xf3
    else if (bx < 448) { cD0 = 128 + (bx - 384) * 4; level = 2; }  // xf2
    else               { cD0 =       (bx - 448) * 4; level = 1; }  // xf1

    if (level == 4) {
        // stage xf4 rows [cX, cX+4) at 32 pts -> s4[j*4+c]
        const int cX = cD0 - 896;
        const float* p = xf4 + ((size_t)b * 1024 + cX) * 32;
        for (int i = tid; i < 4 * 32; i += 256) {
            const int c = i & 3, j = i >> 2;
            s4[i] = p[(size_t)c * 32 + j];
        }
        __syncthreads();
        const int4*  r = recA + (size_t)b * 128;
        const float* w = w1A + (size_t)b * 128;
        for (int q = tid; q < 128; q += 256)
            *(float4*)(s3 + q * 4) = gath4(s4, r[q], w[q]);
        __syncthreads();
    } else if (level == 3) {
        // stage xf3 rows [cA, cA+4) at 128 pts -> s3[j*4+c]
        const int cA = cD0 - 384;
        const float* p = xf3 + ((size_t)b * 512 + cA) * 128;
        for (int i = tid; i < 4 * 128; i += 256) {
            const int c = i & 3, j = i >> 2;
            s3[i] = p[(size_t)c * 128 + j];
        }
        __syncthreads();
    }

    if (level >= 3) {
        const int4*  r = recB + (size_t)b * 512;
        const float* w = w1B + (size_t)b * 512;
        for (int q = tid; q < 512; q += 256)
            *(float4*)(s2 + q * 4) = gath4(s3, r[q], w[q]);
        __syncthreads();
    } else if (level == 2) {
        // stage xf2 rows [cB, cB+4) at 512 pts -> s2[j*4+c]
        const int cB = cD0 - 128;
        const float* p = xf2 + ((size_t)b * 256 + cB) * 512;
        for (int i = tid; i < 4 * 512; i += 256) {
            const int c = i & 3, j = i >> 2;
            s2[i] = p[(size_t)c * 512 + j];
        }
        __syncthreads();
    }

    if (level >= 2) {
        const int4*  r = recC + (size_t)b * 2048;
        const float* w = w1C + (size_t)b * 2048;
        for (int q = tid; q < 2048; q += 256)
            *(float4*)(s + q * 4) = gath4(s2, r[q], w[q]);
    } else {
        // level 1: stage xf1 rows [cD0, cD0+4) at 2048 pts -> s[j*4+c]
        const float* p = xf1 + ((size_t)b * 128 + cD0) * 2048;
        for (int i = tid; i < 4 * 2048; i += 256) {
            const int c = i & 3, j = i >> 2;
            s[i] = p[(size_t)c * 2048 + j];
        }
    }
    __syncthreads();

    // ---- final stage-D interp: 4 queries/thread, float4 stores
    const int4*  rd = recD + (size_t)b * n1;
    const float* wd = w1D + (size_t)b * n1;
    float* outb = out + ((size_t)b * c_out + 64 + cD0) * n1;

#pragma unroll 1
    for (int it = 0; it < 8; ++it) {
        const int q = (it * 256 + tid) * 4;
        const float4 wv = *(const float4*)(wd + q);
        const float4 a0 = gath4(s, rd[q + 0], wv.x);
        const float4 a1 = gath4(s, rd[q + 1], wv.y);
        const float4 a2 = gath4(s, rd[q + 2], wv.z);
        const float4 a3 = gath4(s, rd[q + 3], wv.w);
        *(float4*)(outb + (size_t)0 * n1 + q) = make_float4(a0.x, a1.x, a2.x, a3.x);
        *(float4*)(outb + (size_t)1 * n1 + q) = make_float4(a0.y, a1.y, a2.y, a3.y);
        *(float4*)(outb + (size_t)2 * n1 + q) = make_float4(a0.z, a1.z, a2.z, a3.z);
        *(float4*)(outb + (size_t)3 * n1 + q) = make_float4(a0.w, a1.w, a2.w, a3.w);
    }
}

// ---------------------------------------------------------------------------
extern "C" void kernel_launch(void* const* d_in, const int* in_sizes, int n_in,
                              void* d_out, int out_size, void* d_ws, size_t ws_size,
                              hipStream_t stream)
{
    // setup_inputs order: xyz0, x0, xyz1, x1, xyz2, x2, xyz3, x3, xyz4, x4
    const float* xyz[5];
    const float* xf[5];
    for (int i = 0; i < 5; ++i) {
        xyz[i] = (const float*)d_in[2 * i];
        xf[i]  = (const float*)d_in[2 * i + 1];
    }

    // workspace: only the knn records (no feature intermediates at all)
    char* kb = (char*)d_ws;
    const int n1s[4] = {128, 512, 2048, 8192};  // A, B, C, D query counts
    int4*  rec[4];
    float* w1[4];
    for (int s = 0; s < 4; ++s) { rec[s] = (int4*)kb;  kb += (size_t)B_BATCH * n1s[s] * sizeof(int4); }
    for (int s = 0; s < 4; ++s) { w1[s]  = (float*)kb; kb += (size_t)B_BATCH * n1s[s] * sizeof(float); }

    // --- 1 fused kNN launch (+16 skip-copy blocks riding the idle HBM pipe).
    // Heaviest knn stage's blocks first (longest-job-first).
    KnnAll P;
    P.xq[0]=xyz[0]; P.xs[0]=xyz[1]; P.rec[0]=rec[3]; P.w1[0]=w1[3]; P.n1[0]=8192; P.n2[0]=2048; P.blk0[0]=0;    // D
    P.xq[1]=xyz[1]; P.xs[1]=xyz[2]; P.rec[1]=rec[2]; P.w1[1]=w1[2]; P.n1[1]=2048; P.n2[1]=512;  P.blk0[1]=512;  // C
    P.xq[2]=xyz[2]; P.xs[2]=xyz[3]; P.rec[2]=rec[1]; P.w1[2]=w1[1]; P.n1[2]=512;  P.n2[2]=128;  P.blk0[2]=640;  // B
    P.xq[3]=xyz[3]; P.xs[3]=xyz[4]; P.rec[3]=rec[0]; P.w1[3]=w1[0]; P.n1[3]=128;  P.n2[3]=32;   P.blk0[3]=672;  // A
    {
        dim3 grid(680 + 16, B_BATCH);   // 680 knn blocks + 16 copy blocks
        knn_all_kernel<<<grid, 256, 0, stream>>>(P, xf[0], (float*)d_out);
    }

    // --- 1 mega-kernel: full decoder cascade, writes out[64,1984) directly.
    {
        dim3 grid(480, B_BATCH);
        mega_kernel<<<grid, 256, 0, stream>>>(
            xf[1], xf[2], xf[3], xf[4],
            rec[0], w1[0], rec[1], w1[1], rec[2], w1[2], rec[3], w1[3],
            (float*)d_out);
    }
}

// Round 7
// 348.960 us; speedup vs baseline: 1.1370x; 1.1370x over previous
//
#include <hip/hip_runtime.h>

#define KNN 3
#define EPS 1e-8f
#define B_BATCH 4
#define QPB 16   // queries per block = 4 waves x 4 queries/wave

// ---------------------------------------------------------------------------
// Fused kNN over all 4 stages + the (independent) stage-D skip-copy riding
// along AT THE FRONT of the grid: copy blocks bx<16 are dispatched FIRST so
// the 32 MB xf0 -> out[0,64) HBM copy overlaps the VALU-bound knn scan
// (round-6 placed them last -> they serialized as a tail and regressed).
//
// kNN: wave-per-4-queries; whole xyz2[b] staged in LDS SoA (lane-consecutive
// reads -> 2-way bank aliasing = free). Each lane scans n2/64 candidates for
// 4 queries simultaneously (shared LDS reads, 4 independent branchless top-3
// insert chains on packed u64 keys dist_bits<<32|idx; dist>=0 so float bit
// order == value order; low-word idx tie-breaks to smaller j like jax
// top_k). 6-step __shfl_xor butterfly with a 6-op merge network (lowest-3 of
// two sorted-3 lists). Lane 0 writes a packed record int4{j0,j1,j2,bits(w0n)}
// + w1n; consumer reconstructs w2n = 1 - w0n - w1n.
// ---------------------------------------------------------------------------
__device__ __forceinline__ unsigned long long u64min(unsigned long long a,
                                                     unsigned long long b) {
    return a < b ? a : b;
}
__device__ __forceinline__ unsigned long long u64max(unsigned long long a,
                                                     unsigned long long b) {
    return a > b ? a : b;
}

struct KnnAll {
    const float* xq[4];
    const float* xs[4];
    int4*  rec[4];    // (B, n1): {j0, j1, j2, float_bits(w0n)}
    float* w1[4];     // (B, n1): w1n
    int n1[4], n2[4], blk0[4];
};

__global__ __launch_bounds__(256) void knn_all_kernel(
    KnnAll P,
    const float* __restrict__ xf0,   // (B, 64, 8192) stage-D skip
    float* __restrict__ out)         // (B, 1984, 8192)
{
    __shared__ float s_x[2048], s_y[2048], s_z[2048];
    const int b  = blockIdx.y;
    const int bx = blockIdx.x;

    if (bx < 16) {   // 16 skip-copy blocks FIRST: xf0 -> out[0,64), no deps
        const int t = bx;           // t in [0,16), 4 channels each
        const float4* src = (const float4*)(xf0 + ((size_t)b * 64 + t * 4) * 8192);
        float4*       dst = (float4*)(out + ((size_t)b * 1984 + t * 4) * 8192);
        for (int i = threadIdx.x; i < 4 * 8192 / 4; i += 256)
            dst[i] = src[i];
        return;
    }
    const int bk = bx - 16;   // knn block index in [0, 680)

    // slot selection with CONSTANT struct indices only (runtime-indexed
    // kernarg arrays can spill to scratch -- rule #20)
    const float* xq; const float* xs; int4* orec; float* ow1;
    int n1, n2, bs;
    if (bk >= P.blk0[3]) {
        xq=P.xq[3]; xs=P.xs[3]; orec=P.rec[3]; ow1=P.w1[3];
        n1=P.n1[3]; n2=P.n2[3]; bs=bk-P.blk0[3];
    } else if (bk >= P.blk0[2]) {
        xq=P.xq[2]; xs=P.xs[2]; orec=P.rec[2]; ow1=P.w1[2];
        n1=P.n1[2]; n2=P.n2[2]; bs=bk-P.blk0[2];
    } else if (bk >= P.blk0[1]) {
        xq=P.xq[1]; xs=P.xs[1]; orec=P.rec[1]; ow1=P.w1[1];
        n1=P.n1[1]; n2=P.n2[1]; bs=bk-P.blk0[1];
    } else {
        xq=P.xq[0]; xs=P.xs[0]; orec=P.rec[0]; ow1=P.w1[0];
        n1=P.n1[0]; n2=P.n2[0]; bs=bk;
    }

    const float* src2 = xs + (size_t)b * n2 * 3;
    for (int i = threadIdx.x; i < n2; i += blockDim.x) {
        s_x[i] = src2[i * 3 + 0];
        s_y[i] = src2[i * 3 + 1];
        s_z[i] = src2[i * 3 + 2];
    }
    __syncthreads();

    const int lane = threadIdx.x & 63;
    const int wave = threadIdx.x >> 6;
    const int q0 = bs * QPB + wave * 4;

    float qx[4], qy[4], qz[4];
#pragma unroll
    for (int r = 0; r < 4; ++r) {
        const float* p = xq + ((size_t)b * n1 + q0 + r) * 3;
        qx[r] = p[0]; qy[r] = p[1]; qz[r] = p[2];
    }

    unsigned long long k0[4], k1[4], k2[4];
#pragma unroll
    for (int r = 0; r < 4; ++r) { k0[r] = ~0ull; k1[r] = ~0ull; k2[r] = ~0ull; }

    for (int j = lane; j < n2; j += 64) {
        const float sx = s_x[j], sy = s_y[j], sz = s_z[j];
#pragma unroll
        for (int r = 0; r < 4; ++r) {
            const float dx = qx[r] - sx;
            const float dy = qy[r] - sy;
            const float dz = qz[r] - sz;
            const float d = fmaf(dz, dz, fmaf(dy, dy, dx * dx));
            const unsigned long long key =
                ((unsigned long long)__float_as_uint(d) << 32) | (unsigned)j;
            const unsigned long long u = u64max(key, k0[r]);
            k0[r] = u64min(key, k0[r]);
            const unsigned long long v = u64max(u, k1[r]);
            k1[r] = u64min(u, k1[r]);
            k2[r] = u64min(v, k2[r]);
        }
    }

#pragma unroll
    for (int r = 0; r < 4; ++r) {
        // butterfly merge: both partners compute the same lowest-3 of the
        // two sorted triples (symmetric network), so all lanes converge.
#pragma unroll
        for (int m = 1; m < 64; m <<= 1) {
            const unsigned long long b0 = __shfl_xor(k0[r], m, 64);
            const unsigned long long b1 = __shfl_xor(k1[r], m, 64);
            const unsigned long long b2 = __shfl_xor(k2[r], m, 64);
            const unsigned long long c0 = u64min(k0[r], b0);
            const unsigned long long mm = u64max(k0[r], b0);
            const unsigned long long nn = u64min(k1[r], b1);
            const unsigned long long c1 = u64min(mm, nn);
            const unsigned long long c2 =
                u64min(u64max(mm, nn), u64min(k2[r], b2));
            k0[r] = c0; k1[r] = c1; k2[r] = c2;
        }
        if (lane == 0) {
            const float d0 = __uint_as_float((unsigned)(k0[r] >> 32));
            const float d1 = __uint_as_float((unsigned)(k1[r] >> 32));
            const float d2 = __uint_as_float((unsigned)(k2[r] >> 32));
            float w0 = 1.0f / (d0 + EPS);
            float w1 = 1.0f / (d1 + EPS);
            float w2 = 1.0f / (d2 + EPS);
            const float inv = 1.0f / (w0 + w1 + w2);
            const size_t o = (size_t)b * n1 + q0 + r;
            int4 rec;
            rec.x = (int)(unsigned)(k0[r] & 0xFFFFFFFFu);
            rec.y = (int)(unsigned)(k1[r] & 0xFFFFFFFFu);
            rec.z = (int)(unsigned)(k2[r] & 0xFFFFFFFFu);
            rec.w = __float_as_int(w0 * inv);
            orec[o] = rec;
            ow1[o]  = w1 * inv;
        }
    }
}

// ---------------------------------------------------------------------------
// Mega-kernel: the ENTIRE decoder cascade in one launch (round-4-proven).
// Channel mapping is bijective end-to-end: D output tile [64+cD0, 64+cD0+4)
// consumes exactly stage-C channels cD0..cD0+3, which consume B channels
// cD0-128, which consume A channels cD0-384, which consume xf4 channels
// cD0-896. Each block starts at the shallowest level that sources its 4
// channels from a real input, then gathers up the cascade entirely in LDS:
//   32 pts (s4) --recA--> 128 (s3) --recB--> 512 (s2) --recC--> 2048 (s)
//   --recD--> 8192 output rows.
// s3/s4 are aliased into s (dead by the time s is written) -> 40 KB LDS.
// Phase 2 is the proven scalar loop: 1 query/thread, 3 ds_read_b128 gathers,
// scalar coalesced stores. (Round-6's float4 4-query variant regressed; no
// launch_bounds min-waves cap -- round 2 showed spills regress this.)
// ---------------------------------------------------------------------------
__device__ __forceinline__ float4 gath4(const float* s, const int4 r,
                                        const float w1) {
    const float w0 = __int_as_float(r.w);
    const float w2 = 1.0f - w0 - w1;
    const float4 g0 = *(const float4*)(s + r.x * 4);
    const float4 g1 = *(const float4*)(s + r.y * 4);
    const float4 g2 = *(const float4*)(s + r.z * 4);
    float4 v;
    v.x = w0 * g0.x + w1 * g1.x + w2 * g2.x;
    v.y = w0 * g0.y + w1 * g1.y + w2 * g2.y;
    v.z = w0 * g0.z + w1 * g1.z + w2 * g2.z;
    v.w = w0 * g0.w + w1 * g1.w + w2 * g2.w;
    return v;
}

__global__ __launch_bounds__(256) void mega_kernel(
    const float* __restrict__ xf1,   // (B,  128, 2048)
    const float* __restrict__ xf2,   // (B,  256,  512)
    const float* __restrict__ xf3,   // (B,  512,  128)
    const float* __restrict__ xf4,   // (B, 1024,   32)
    const int4*  __restrict__ recA, const float* __restrict__ w1A,  // (B,128)
    const int4*  __restrict__ recB, const float* __restrict__ w1B,  // (B,512)
    const int4*  __restrict__ recC, const float* __restrict__ w1C,  // (B,2048)
    const int4*  __restrict__ recD, const float* __restrict__ w1D,  // (B,8192)
    float* __restrict__ out)         // (B, 1984, 8192)
{
    const int n1 = 8192, c_out = 1984;
    __shared__ __align__(16) float s [2048 * 4];   // 32 KB, s[j*4+c]
    __shared__ __align__(16) float s2[ 512 * 4];   //  8 KB
    float* s3 = s;         // 128*4 floats, aliased: dead before s is written
    float* s4 = s + 512;   //  32*4 floats, disjoint from s3

    const int b   = blockIdx.y;
    const int bx  = blockIdx.x;
    const int tid = threadIdx.x;

    // longest-cascade-first block ordering (all branches block-uniform)
    int cD0, level;
    if (bx < 256)      { cD0 = 896 + bx * 4;         level = 4; }  // xf4 deep
    else if (bx < 384) { cD0 = 384 + (bx - 256) * 4; level = 3; }  // xf3
    else if (bx < 448) { cD0 = 128 + (bx - 384) * 4; level = 2; }  // xf2
    else               { cD0 =       (bx - 448) * 4; level = 1; }  // xf1

    if (level == 4) {
        // stage xf4 rows [cX, cX+4) at 32 pts -> s4[j*4+c]
        const int cX = cD0 - 896;
        const float* p = xf4 + ((size_t)b * 1024 + cX) * 32;
        for (int i = tid; i < 4 * 32; i += 256) {
            const int c = i & 3, j = i >> 2;
            s4[i] = p[(size_t)c * 32 + j];
        }
        __syncthreads();
        const int4*  r = recA + (size_t)b * 128;
        const float* w = w1A + (size_t)b * 128;
        for (int q = tid; q < 128; q += 256)
            *(float4*)(s3 + q * 4) = gath4(s4, r[q], w[q]);
        __syncthreads();
    } else if (level == 3) {
        // stage xf3 rows [cA, cA+4) at 128 pts -> s3[j*4+c]
        const int cA = cD0 - 384;
        const float* p = xf3 + ((size_t)b * 512 + cA) * 128;
        for (int i = tid; i < 4 * 128; i += 256) {
            const int c = i & 3, j = i >> 2;
            s3[i] = p[(size_t)c * 128 + j];
        }
        __syncthreads();
    }

    if (level >= 3) {
        const int4*  r = recB + (size_t)b * 512;
        const float* w = w1B + (size_t)b * 512;
        for (int q = tid; q < 512; q += 256)
            *(float4*)(s2 + q * 4) = gath4(s3, r[q], w[q]);
        __syncthreads();
    } else if (level == 2) {
        // stage xf2 rows [cB, cB+4) at 512 pts -> s2[j*4+c]
        const int cB = cD0 - 128;
        const float* p = xf2 + ((size_t)b * 256 + cB) * 512;
        for (int i = tid; i < 4 * 512; i += 256) {
            const int c = i & 3, j = i >> 2;
            s2[i] = p[(size_t)c * 512 + j];
        }
        __syncthreads();
    }

    if (level >= 2) {
        const int4*  r = recC + (size_t)b * 2048;
        const float* w = w1C + (size_t)b * 2048;
        for (int q = tid; q < 2048; q += 256)
            *(float4*)(s + q * 4) = gath4(s2, r[q], w[q]);
    } else {
        // level 1: stage xf1 rows [cD0, cD0+4) at 2048 pts -> s[j*4+c]
        const float* p = xf1 + ((size_t)b * 128 + cD0) * 2048;
        for (int i = tid; i < 4 * 2048; i += 256) {
            const int c = i & 3, j = i >> 2;
            s[i] = p[(size_t)c * 2048 + j];
        }
    }
    __syncthreads();

    // ---- final stage-D interp, 1 query/thread (round-4-proven codegen)
    const int4*  rd = recD + (size_t)b * n1;
    const float* wd = w1D + (size_t)b * n1;
    float* outb = out + ((size_t)b * c_out + 64 + cD0) * n1;

    for (int q = tid; q < n1; q += 256) {
        const int4 r  = rd[q];
        const float w0 = __int_as_float(r.w);
        const float w1 = wd[q];
        const float w2 = 1.0f - w0 - w1;
        const float4 v0 = *(const float4*)(s + r.x * 4);
        const float4 v1 = *(const float4*)(s + r.y * 4);
        const float4 v2 = *(const float4*)(s + r.z * 4);
        outb[(size_t)0 * n1 + q] = w0 * v0.x + w1 * v1.x + w2 * v2.x;
        outb[(size_t)1 * n1 + q] = w0 * v0.y + w1 * v1.y + w2 * v2.y;
        outb[(size_t)2 * n1 + q] = w0 * v0.z + w1 * v1.z + w2 * v2.z;
        outb[(size_t)3 * n1 + q] = w0 * v0.w + w1 * v1.w + w2 * v2.w;
    }
}

// ---------------------------------------------------------------------------
extern "C" void kernel_launch(void* const* d_in, const int* in_sizes, int n_in,
                              void* d_out, int out_size, void* d_ws, size_t ws_size,
                              hipStream_t stream)
{
    // setup_inputs order: xyz0, x0, xyz1, x1, xyz2, x2, xyz3, x3, xyz4, x4
    const float* xyz[5];
    const float* xf[5];
    for (int i = 0; i < 5; ++i) {
        xyz[i] = (const float*)d_in[2 * i];
        xf[i]  = (const float*)d_in[2 * i + 1];
    }

    // workspace: only the knn records (no feature intermediates at all)
    char* kb = (char*)d_ws;
    const int n1s[4] = {128, 512, 2048, 8192};  // A, B, C, D query counts
    int4*  rec[4];
    float* w1[4];
    for (int s = 0; s < 4; ++s) { rec[s] = (int4*)kb;  kb += (size_t)B_BATCH * n1s[s] * sizeof(int4); }
    for (int s = 0; s < 4; ++s) { w1[s]  = (float*)kb; kb += (size_t)B_BATCH * n1s[s] * sizeof(float); }

    // --- 1 fused kNN launch; 16 skip-copy blocks dispatched FIRST (overlap
    // the VALU-bound knn scan), then knn blocks longest-job-first.
    KnnAll P;
    P.xq[0]=xyz[0]; P.xs[0]=xyz[1]; P.rec[0]=rec[3]; P.w1[0]=w1[3]; P.n1[0]=8192; P.n2[0]=2048; P.blk0[0]=0;    // D
    P.xq[1]=xyz[1]; P.xs[1]=xyz[2]; P.rec[1]=rec[2]; P.w1[1]=w1[2]; P.n1[1]=2048; P.n2[1]=512;  P.blk0[1]=512;  // C
    P.xq[2]=xyz[2]; P.xs[2]=xyz[3]; P.rec[2]=rec[1]; P.w1[2]=w1[1]; P.n1[2]=512;  P.n2[2]=128;  P.blk0[2]=640;  // B
    P.xq[3]=xyz[3]; P.xs[3]=xyz[4]; P.rec[3]=rec[0]; P.w1[3]=w1[0]; P.n1[3]=128;  P.n2[3]=32;   P.blk0[3]=672;  // A
    {
        dim3 grid(16 + 680, B_BATCH);   // 16 copy blocks first + 680 knn
        knn_all_kernel<<<grid, 256, 0, stream>>>(P, xf[0], (float*)d_out);
    }

    // --- 1 mega-kernel: full decoder cascade, writes out[64,1984) directly.
    {
        dim3 grid(480, B_BATCH);
        mega_kernel<<<grid, 256, 0, stream>>>(
            xf[1], xf[2], xf[3], xf[4],
            rec[0], w1[0], rec[1], w1[1], rec[2], w1[2], rec[3], w1[3],
            (float*)d_out);
    }
}

// Round 8
// 346.377 us; speedup vs baseline: 1.1455x; 1.0075x over previous
//
#include <hip/hip_runtime.h>

#define KNN 3
#define EPS 1e-8f
#define B_BATCH 4
#define QPB 16   // queries per block = 4 waves x 4 queries/wave

// ---------------------------------------------------------------------------
// Fused kNN over all 4 stages + the (independent) stage-D skip-copy riding
// along AT THE FRONT of the grid: copy blocks bx<16 are dispatched FIRST so
// the 32 MB xf0 -> out[0,64) HBM copy overlaps the VALU-bound knn scan
// (round-6 placed them last -> tail serialization, regressed; round-7 front
// placement measured -17 us).
//
// kNN: wave-per-4-queries; whole xyz2[b] staged in LDS SoA (lane-consecutive
// reads -> 2-way bank aliasing = free). Each lane scans n2/64 candidates for
// 4 queries simultaneously (shared LDS reads, 4 independent branchless top-3
// insert chains on packed u64 keys dist_bits<<32|idx; dist>=0 so float bit
// order == value order; low-word idx tie-breaks to smaller j like jax
// top_k). 6-step __shfl_xor butterfly with a 6-op merge network (lowest-3 of
// two sorted-3 lists). Lane 0 writes ONE packed int4 record per query:
//   {j0 | j1<<16, j2, bits(w0n), bits(w1n)}   (all n2 <= 2048 -> 16-bit idx)
// so every consumer gather is a single 16 B load; w2n = 1 - w0n - w1n.
// ---------------------------------------------------------------------------
__device__ __forceinline__ unsigned long long u64min(unsigned long long a,
                                                     unsigned long long b) {
    return a < b ? a : b;
}
__device__ __forceinline__ unsigned long long u64max(unsigned long long a,
                                                     unsigned long long b) {
    return a > b ? a : b;
}

struct KnnAll {
    const float* xq[4];
    const float* xs[4];
    int4*  rec[4];    // (B, n1): {j0|j1<<16, j2, bits(w0n), bits(w1n)}
    int n1[4], n2[4], blk0[4];
};

__global__ __launch_bounds__(256) void knn_all_kernel(
    KnnAll P,
    const float* __restrict__ xf0,   // (B, 64, 8192) stage-D skip
    float* __restrict__ out)         // (B, 1984, 8192)
{
    __shared__ float s_x[2048], s_y[2048], s_z[2048];
    const int b  = blockIdx.y;
    const int bx = blockIdx.x;

    if (bx < 16) {   // 16 skip-copy blocks FIRST: xf0 -> out[0,64), no deps
        const int t = bx;           // t in [0,16), 4 channels each
        const float4* src = (const float4*)(xf0 + ((size_t)b * 64 + t * 4) * 8192);
        float4*       dst = (float4*)(out + ((size_t)b * 1984 + t * 4) * 8192);
        for (int i = threadIdx.x; i < 4 * 8192 / 4; i += 256)
            dst[i] = src[i];
        return;
    }
    const int bk = bx - 16;   // knn block index in [0, 680)

    // slot selection with CONSTANT struct indices only (runtime-indexed
    // kernarg arrays can spill to scratch -- rule #20)
    const float* xq; const float* xs; int4* orec;
    int n1, n2, bs;
    if (bk >= P.blk0[3]) {
        xq=P.xq[3]; xs=P.xs[3]; orec=P.rec[3];
        n1=P.n1[3]; n2=P.n2[3]; bs=bk-P.blk0[3];
    } else if (bk >= P.blk0[2]) {
        xq=P.xq[2]; xs=P.xs[2]; orec=P.rec[2];
        n1=P.n1[2]; n2=P.n2[2]; bs=bk-P.blk0[2];
    } else if (bk >= P.blk0[1]) {
        xq=P.xq[1]; xs=P.xs[1]; orec=P.rec[1];
        n1=P.n1[1]; n2=P.n2[1]; bs=bk-P.blk0[1];
    } else {
        xq=P.xq[0]; xs=P.xs[0]; orec=P.rec[0];
        n1=P.n1[0]; n2=P.n2[0]; bs=bk;
    }

    const float* src2 = xs + (size_t)b * n2 * 3;
    for (int i = threadIdx.x; i < n2; i += blockDim.x) {
        s_x[i] = src2[i * 3 + 0];
        s_y[i] = src2[i * 3 + 1];
        s_z[i] = src2[i * 3 + 2];
    }
    __syncthreads();

    const int lane = threadIdx.x & 63;
    const int wave = threadIdx.x >> 6;
    const int q0 = bs * QPB + wave * 4;

    float qx[4], qy[4], qz[4];
#pragma unroll
    for (int r = 0; r < 4; ++r) {
        const float* p = xq + ((size_t)b * n1 + q0 + r) * 3;
        qx[r] = p[0]; qy[r] = p[1]; qz[r] = p[2];
    }

    unsigned long long k0[4], k1[4], k2[4];
#pragma unroll
    for (int r = 0; r < 4; ++r) { k0[r] = ~0ull; k1[r] = ~0ull; k2[r] = ~0ull; }

    for (int j = lane; j < n2; j += 64) {
        const float sx = s_x[j], sy = s_y[j], sz = s_z[j];
#pragma unroll
        for (int r = 0; r < 4; ++r) {
            const float dx = qx[r] - sx;
            const float dy = qy[r] - sy;
            const float dz = qz[r] - sz;
            const float d = fmaf(dz, dz, fmaf(dy, dy, dx * dx));
            const unsigned long long key =
                ((unsigned long long)__float_as_uint(d) << 32) | (unsigned)j;
            const unsigned long long u = u64max(key, k0[r]);
            k0[r] = u64min(key, k0[r]);
            const unsigned long long v = u64max(u, k1[r]);
            k1[r] = u64min(u, k1[r]);
            k2[r] = u64min(v, k2[r]);
        }
    }

#pragma unroll
    for (int r = 0; r < 4; ++r) {
        // butterfly merge: both partners compute the same lowest-3 of the
        // two sorted triples (symmetric network), so all lanes converge.
#pragma unroll
        for (int m = 1; m < 64; m <<= 1) {
            const unsigned long long b0 = __shfl_xor(k0[r], m, 64);
            const unsigned long long b1 = __shfl_xor(k1[r], m, 64);
            const unsigned long long b2 = __shfl_xor(k2[r], m, 64);
            const unsigned long long c0 = u64min(k0[r], b0);
            const unsigned long long mm = u64max(k0[r], b0);
            const unsigned long long nn = u64min(k1[r], b1);
            const unsigned long long c1 = u64min(mm, nn);
            const unsigned long long c2 =
                u64min(u64max(mm, nn), u64min(k2[r], b2));
            k0[r] = c0; k1[r] = c1; k2[r] = c2;
        }
        if (lane == 0) {
            const float d0 = __uint_as_float((unsigned)(k0[r] >> 32));
            const float d1 = __uint_as_float((unsigned)(k1[r] >> 32));
            const float d2 = __uint_as_float((unsigned)(k2[r] >> 32));
            float w0 = 1.0f / (d0 + EPS);
            float w1 = 1.0f / (d1 + EPS);
            float w2 = 1.0f / (d2 + EPS);
            const float inv = 1.0f / (w0 + w1 + w2);
            int4 rec;
            rec.x = (int)((k0[r] & 0xFFFFu) | ((k1[r] & 0xFFFFu) << 16));
            rec.y = (int)(unsigned)(k2[r] & 0xFFFFFFFFu);
            rec.z = __float_as_int(w0 * inv);
            rec.w = __float_as_int(w1 * inv);
            orec[(size_t)b * n1 + q0 + r] = rec;
        }
    }
}

// ---------------------------------------------------------------------------
// Mega-kernel: the ENTIRE decoder cascade in one launch (round-4-proven).
// Channel mapping is bijective end-to-end: D output tile [64+cD0, 64+cD0+4)
// consumes exactly stage-C channels cD0..cD0+3, which consume B channels
// cD0-128, which consume A channels cD0-384, which consume xf4 channels
// cD0-896. Each block starts at the shallowest level that sources its 4
// channels from a real input, then gathers up the cascade entirely in LDS:
//   32 pts (s4) --recA--> 128 (s3) --recB--> 512 (s2) --recC--> 2048 (s)
//   --recD--> 8192 output rows.
// s3/s4 are aliased into s (dead by the time s is written) -> 40 KB LDS.
// Phase 2 is the proven scalar loop: 1 query/thread, ONE int4 rec load,
// 3 ds_read_b128 gathers, scalar coalesced stores. (Round-6's float4
// 4-query variant regressed; no launch_bounds min-waves cap -- round 2
// showed spills regress this.)
// ---------------------------------------------------------------------------
__device__ __forceinline__ float4 gath4(const float* s, const int4 p) {
    const int   j0 = p.x & 0xFFFF;
    const int   j1 = ((unsigned)p.x) >> 16;
    const int   j2 = p.y;
    const float w0 = __int_as_float(p.z);
    const float w1 = __int_as_float(p.w);
    const float w2 = 1.0f - w0 - w1;
    const float4 g0 = *(const float4*)(s + j0 * 4);
    const float4 g1 = *(const float4*)(s + j1 * 4);
    const float4 g2 = *(const float4*)(s + j2 * 4);
    float4 v;
    v.x = w0 * g0.x + w1 * g1.x + w2 * g2.x;
    v.y = w0 * g0.y + w1 * g1.y + w2 * g2.y;
    v.z = w0 * g0.z + w1 * g1.z + w2 * g2.z;
    v.w = w0 * g0.w + w1 * g1.w + w2 * g2.w;
    return v;
}

__global__ __launch_bounds__(256) void mega_kernel(
    const float* __restrict__ xf1,   // (B,  128, 2048)
    const float* __restrict__ xf2,   // (B,  256,  512)
    const float* __restrict__ xf3,   // (B,  512,  128)
    const float* __restrict__ xf4,   // (B, 1024,   32)
    const int4*  __restrict__ recA,  // (B,  128)
    const int4*  __restrict__ recB,  // (B,  512)
    const int4*  __restrict__ recC,  // (B, 2048)
    const int4*  __restrict__ recD,  // (B, 8192)
    float* __restrict__ out)         // (B, 1984, 8192)
{
    const int n1 = 8192, c_out = 1984;
    __shared__ __align__(16) float s [2048 * 4];   // 32 KB, s[j*4+c]
    __shared__ __align__(16) float s2[ 512 * 4];   //  8 KB
    float* s3 = s;         // 128*4 floats, aliased: dead before s is written
    float* s4 = s + 512;   //  32*4 floats, disjoint from s3

    const int b   = blockIdx.y;
    const int bx  = blockIdx.x;
    const int tid = threadIdx.x;

    // longest-cascade-first block ordering (all branches block-uniform)
    int cD0, level;
    if (bx < 256)      { cD0 = 896 + bx * 4;         level = 4; }  // xf4 deep
    else if (bx < 384) { cD0 = 384 + (bx - 256) * 4; level = 3; }  // xf3
    else if (bx < 448) { cD0 = 128 + (bx - 384) * 4; level = 2; }  // xf2
    else               { cD0 =       (bx - 448) * 4; level = 1; }  // xf1

    if (level == 4) {
        // stage xf4 rows [cX, cX+4) at 32 pts -> s4[j*4+c]
        const int cX = cD0 - 896;
        const float* p = xf4 + ((size_t)b * 1024 + cX) * 32;
        for (int i = tid; i < 4 * 32; i += 256) {
            const int c = i & 3, j = i >> 2;
            s4[i] = p[(size_t)c * 32 + j];
        }
        __syncthreads();
        const int4* r = recA + (size_t)b * 128;
        for (int q = tid; q < 128; q += 256)
            *(float4*)(s3 + q * 4) = gath4(s4, r[q]);
        __syncthreads();
    } else if (level == 3) {
        // stage xf3 rows [cA, cA+4) at 128 pts -> s3[j*4+c]
        const int cA = cD0 - 384;
        const float* p = xf3 + ((size_t)b * 512 + cA) * 128;
        for (int i = tid; i < 4 * 128; i += 256) {
            const int c = i & 3, j = i >> 2;
            s3[i] = p[(size_t)c * 128 + j];
        }
        __syncthreads();
    }

    if (level >= 3) {
        const int4* r = recB + (size_t)b * 512;
        for (int q = tid; q < 512; q += 256)
            *(float4*)(s2 + q * 4) = gath4(s3, r[q]);
        __syncthreads();
    } else if (level == 2) {
        // stage xf2 rows [cB, cB+4) at 512 pts -> s2[j*4+c]
        const int cB = cD0 - 128;
        const float* p = xf2 + ((size_t)b * 256 + cB) * 512;
        for (int i = tid; i < 4 * 512; i += 256) {
            const int c = i & 3, j = i >> 2;
            s2[i] = p[(size_t)c * 512 + j];
        }
        __syncthreads();
    }

    if (level >= 2) {
        const int4* r = recC + (size_t)b * 2048;
        for (int q = tid; q < 2048; q += 256)
            *(float4*)(s + q * 4) = gath4(s2, r[q]);
    } else {
        // level 1: stage xf1 rows [cD0, cD0+4) at 2048 pts -> s[j*4+c]
        const float* p = xf1 + ((size_t)b * 128 + cD0) * 2048;
        for (int i = tid; i < 4 * 2048; i += 256) {
            const int c = i & 3, j = i >> 2;
            s[i] = p[(size_t)c * 2048 + j];
        }
    }
    __syncthreads();

    // ---- final stage-D interp, 1 query/thread (round-4-proven codegen)
    const int4* rd = recD + (size_t)b * n1;
    float* outb = out + ((size_t)b * c_out + 64 + cD0) * n1;

    for (int q = tid; q < n1; q += 256) {
        const float4 v = gath4(s, rd[q]);
        outb[(size_t)0 * n1 + q] = v.x;
        outb[(size_t)1 * n1 + q] = v.y;
        outb[(size_t)2 * n1 + q] = v.z;
        outb[(size_t)3 * n1 + q] = v.w;
    }
}

// ---------------------------------------------------------------------------
extern "C" void kernel_launch(void* const* d_in, const int* in_sizes, int n_in,
                              void* d_out, int out_size, void* d_ws, size_t ws_size,
                              hipStream_t stream)
{
    // setup_inputs order: xyz0, x0, xyz1, x1, xyz2, x2, xyz3, x3, xyz4, x4
    const float* xyz[5];
    const float* xf[5];
    for (int i = 0; i < 5; ++i) {
        xyz[i] = (const float*)d_in[2 * i];
        xf[i]  = (const float*)d_in[2 * i + 1];
    }

    // workspace: only the packed knn records
    char* kb = (char*)d_ws;
    const int n1s[4] = {128, 512, 2048, 8192};  // A, B, C, D query counts
    int4* rec[4];
    for (int s = 0; s < 4; ++s) { rec[s] = (int4*)kb; kb += (size_t)B_BATCH * n1s[s] * sizeof(int4); }

    // --- 1 fused kNN launch; 16 skip-copy blocks dispatched FIRST (overlap
    // the VALU-bound knn scan), then knn blocks longest-job-first.
    KnnAll P;
    P.xq[0]=xyz[0]; P.xs[0]=xyz[1]; P.rec[0]=rec[3]; P.n1[0]=8192; P.n2[0]=2048; P.blk0[0]=0;    // D
    P.xq[1]=xyz[1]; P.xs[1]=xyz[2]; P.rec[1]=rec[2]; P.n1[1]=2048; P.n2[1]=512;  P.blk0[1]=512;  // C
    P.xq[2]=xyz[2]; P.xs[2]=xyz[3]; P.rec[2]=rec[1]; P.n1[2]=512;  P.n2[2]=128;  P.blk0[2]=640;  // B
    P.xq[3]=xyz[3]; P.xs[3]=xyz[4]; P.rec[3]=rec[0]; P.n1[3]=128;  P.n2[3]=32;   P.blk0[3]=672;  // A
    {
        dim3 grid(16 + 680, B_BATCH);   // 16 copy blocks first + 680 knn
        knn_all_kernel<<<grid, 256, 0, stream>>>(P, xf[0], (float*)d_out);
    }

    // --- 1 mega-kernel: full decoder cascade, writes out[64,1984) directly.
    {
        dim3 grid(480, B_BATCH);
        mega_kernel<<<grid, 256, 0, stream>>>(
            xf[1], xf[2], xf[3], xf[4],
            rec[0], rec[1], rec[2], rec[3],
            (float*)d_out);
    }
}